// Round 7
// baseline (906.958 us; speedup 1.0000x reference)
//
#include <hip/hip_runtime.h>

#define B_ 32
#define C_ 256
#define T_ 2048
#define N_ 65536      // B_*T_
#define NE_ 1024
#define NELEM 16777216  // B_*C_*T_
#define TAU 1.75e-4f    // repair window: np fp32 quantization (~3.2e-5) + f16-split GEMM noise (~4e-5), 2x margin
#define WLCAP 16384
#define RPB 8           // flagged rows per repair block

typedef _Float16 half8 __attribute__((ext_vector_type(8)));
typedef float f32x16 __attribute__((ext_vector_type(16)));

// d_ws layout (4-byte units):
// [0,1024)        counts (int)
// [1024,2048)     enorm (float, fl32 of fp64-exact ||e||^2)
// [2048]          sse (float)
// [2049]          nflag (int)
// [4608,70144)    idx (int)
// [70144,86528)   worklist (int)
// [98304,229376)  ebuf: e as f16 in MFMA B-fragment order (512 KB)

__global__ void k_prep(const float* __restrict__ emb, half8* __restrict__ ebuf,
                       float* __restrict__ enorm) {
  int code = blockIdx.x * blockDim.x + threadIdx.x;  // 0..1023
  const float4* row = reinterpret_cast<const float4*>(emb + (size_t)code * C_);
  double s = 0.0;
#pragma unroll
  for (int k = 0; k < C_ / 4; ++k) {
    float4 v = row[k];
    s = fma((double)v.x, (double)v.x, s);
    s = fma((double)v.y, (double)v.y, s);
    s = fma((double)v.z, (double)v.z, s);
    s = fma((double)v.w, (double)v.w, s);
  }
  enorm[code] = (float)s;
  const int nt = code >> 5, lcol = code & 31;
#pragma unroll
  for (int s16 = 0; s16 < 16; ++s16) {
#pragma unroll
    for (int h2 = 0; h2 < 2; ++h2) {
      float4 v0 = row[s16 * 4 + h2 * 2];
      float4 v1 = row[s16 * 4 + h2 * 2 + 1];
      half8 hv;
      hv[0] = (_Float16)v0.x; hv[1] = (_Float16)v0.y;
      hv[2] = (_Float16)v0.z; hv[3] = (_Float16)v0.w;
      hv[4] = (_Float16)v1.x; hv[5] = (_Float16)v1.y;
      hv[6] = (_Float16)v1.z; hv[7] = (_Float16)v1.w;
      ebuf[(nt * 16 + s16) * 64 + h2 * 32 + lcol] = hv;
    }
  }
}

// MFMA VQ, code-split: each wave scores 32 rows x 512 codes (half the nt range);
// wave pairs {w, w^1} cover the same 32 rows with disjoint code halves and are
// merged exactly (top-2, lowest-index ties) via LDS. Per-(row,code) arithmetic
// is bit-identical to the previous passing version.
__launch_bounds__(256, 4)
__global__ void k_vq(const float* __restrict__ z, const half8* __restrict__ ebuf,
                     const float* __restrict__ enorm, int* __restrict__ idx_i,
                     float* __restrict__ idx_f, int* __restrict__ counts,
                     int* __restrict__ nflag, int* __restrict__ worklist) {
  __shared__ float sm1[2][64], sm2[2][64];
  __shared__ int smi[2][64];
  const int tid = threadIdx.x;
  const int w = tid >> 6;        // wave 0..3
  const int l = tid & 63;
  const int lcol = l & 31;       // A-row slot / B-col slot
  const int h2 = l >> 5;         // k-group
  const int half = w & 1;        // code half: 0 -> codes 0..511, 1 -> 512..1023
  const int rowg = (w >> 1) << 5;  // row group within block: 0 or 32
  const int n0 = blockIdx.x * 64;
  const int b = n0 >> 11;
  const int t = (n0 & (T_ - 1)) + rowg + lcol;
  const float* zcol = z + (size_t)b * C_ * T_ + t;

  half8 Ah[16], Al[16];
#pragma unroll
  for (int s = 0; s < 16; ++s) {
    half8 hv, lv;
#pragma unroll
    for (int i = 0; i < 8; ++i) {
      float zf = zcol[(size_t)(16 * s + 8 * h2 + i) * T_];
      _Float16 hh = (_Float16)zf;
      hv[i] = hh;
      lv[i] = (_Float16)(zf - (float)hh);
    }
    Ah[s] = hv; Al[s] = lv;
  }

  f32x16 Z;
#pragma unroll
  for (int r = 0; r < 16; ++r) Z[r] = 0.f;

  float b1s[16], b2s[16]; int b1i[16];
#pragma unroll
  for (int r = 0; r < 16; ++r) { b1s[r] = 3.4e38f; b2s[r] = 3.4e38f; b1i[r] = 0; }

  const half8* bp = ebuf + l;
  for (int nt = half * 16; nt < half * 16 + 16; ++nt) {
    f32x16 ah = Z, al = Z;
#pragma unroll
    for (int s = 0; s < 16; ++s) {
      half8 bf = bp[(nt * 16 + s) * 64];
      ah = __builtin_amdgcn_mfma_f32_32x32x16_f16(Ah[s], bf, ah, 0, 0, 0);
      al = __builtin_amdgcn_mfma_f32_32x32x16_f16(Al[s], bf, al, 0, 0, 0);
    }
    const int codeb = (nt << 5) + lcol;
    const float en = enorm[codeb];
#pragma unroll
    for (int r = 0; r < 16; ++r) {
      float sc = fmaf(-2.f, ah[r] + al[r], en);
      float nb2 = fminf(b2s[r], fmaxf(b1s[r], sc));
      bool lt = sc < b1s[r];
      b2s[r] = nb2;
      b1i[r] = lt ? codeb : b1i[r];
      b1s[r] = fminf(b1s[r], sc);
    }
  }
  // merge top-2 across the 32 code-lanes of this wave
#pragma unroll
  for (int m = 1; m < 32; m <<= 1) {
#pragma unroll
    for (int r = 0; r < 16; ++r) {
      float o1 = __shfl_xor(b1s[r], m);
      int oi = __shfl_xor(b1i[r], m);
      float o2 = __shfl_xor(b2s[r], m);
      float hi = fmaxf(b1s[r], o1);
      b2s[r] = fminf(fminf(b2s[r], o2), hi);
      if (o1 < b1s[r] || (o1 == b1s[r] && oi < b1i[r])) { b1s[r] = o1; b1i[r] = oi; }
    }
  }
  if (lcol == 0) {
#pragma unroll
    for (int r = 0; r < 16; ++r) {
      int row = rowg + (r & 3) + ((r >> 2) << 3) + (h2 << 2);
      sm1[half][row] = b1s[r];
      sm2[half][row] = b2s[r];
      smi[half][row] = b1i[r];
    }
  }
  __syncthreads();
  // exact cross-half merge: one thread per row
  if (tid < 64) {
    float s1a = sm1[0][tid], s2a = sm2[0][tid]; int i1a = smi[0][tid];
    float s1b = sm1[1][tid], s2b = sm2[1][tid]; int i1b = smi[1][tid];
    float b1, b2; int i1;
    if (s1b < s1a) { b1 = s1b; i1 = i1b; b2 = fminf(s2b, s1a); }
    else           { b1 = s1a; i1 = i1a; b2 = fminf(s2a, s1b); }  // tie -> lower codes (half 0)
    int n = n0 + tid;
    idx_i[n] = i1;
    idx_f[n] = (float)i1;
    atomicAdd(&counts[i1], 1);
    if (b2 - b1 < TAU) {
      int p = atomicAdd(nflag, 1);
      if (p < WLCAP) worklist[p] = n;
    }
  }
}

// Re-score flagged rows (batched RPB per block) emulating numpy's fp32 arithmetic.
__global__ void k_repair(const float* __restrict__ z, const float* __restrict__ emb,
                         const float* __restrict__ enorm,
                         const int* __restrict__ nflag, const int* __restrict__ worklist,
                         int* __restrict__ idx_i, float* __restrict__ idx_f,
                         int* __restrict__ counts) {
  __shared__ float4 zs4[RPB][C_ / 4];
  __shared__ double wred[4][RPB];
  __shared__ float szf[RPB];
  __shared__ float rs[RPB][256];
  __shared__ int ri[RPB][256];
  const int tid = threadIdx.x;
  int cnt = nflag[0];
  if (cnt > WLCAP) cnt = WLCAP;
  const int nbatch = (cnt + RPB - 1) / RPB;
  for (int batch = blockIdx.x; batch < nbatch; batch += gridDim.x) {
    const int base = batch * RPB;
    double p[RPB];
#pragma unroll
    for (int r = 0; r < RPB; ++r) {
      int wi = base + r;
      int n = worklist[wi < cnt ? wi : base];
      int b = n >> 11, t = n & (T_ - 1);
      float zv = z[(size_t)b * C_ * T_ + (size_t)tid * T_ + t];
      reinterpret_cast<float*>(&zs4[r][0])[tid] = zv;
      p[r] = (double)zv * (double)zv;
    }
#pragma unroll
    for (int m = 32; m > 0; m >>= 1)
#pragma unroll
      for (int r = 0; r < RPB; ++r) p[r] += __shfl_down(p[r], m);
    if ((tid & 63) == 0)
#pragma unroll
      for (int r = 0; r < RPB; ++r) wred[tid >> 6][r] = p[r];
    __syncthreads();
    if (tid < RPB)
      szf[tid] = (float)(wred[0][tid] + wred[1][tid] + wred[2][tid] + wred[3][tid]);
    __syncthreads();

    float bd[RPB]; int bi[RPB];
#pragma unroll
    for (int r = 0; r < RPB; ++r) { bd[r] = 3.4e38f; bi[r] = 1 << 30; }
#pragma unroll
    for (int rep = 0; rep < 4; ++rep) {
      const int j = rep * 256 + tid;
      const float4* er = reinterpret_cast<const float4*>(emb + (size_t)j * C_);
      float acc[RPB];
#pragma unroll
      for (int r = 0; r < RPB; ++r) acc[r] = 0.f;
#pragma unroll 8
      for (int k4 = 0; k4 < C_ / 4; ++k4) {
        float4 ev = er[k4];
#pragma unroll
        for (int r = 0; r < RPB; ++r) {
          float4 zv = zs4[r][k4];
          acc[r] = fmaf(zv.x, ev.x, acc[r]);
          acc[r] = fmaf(zv.y, ev.y, acc[r]);
          acc[r] = fmaf(zv.z, ev.z, acc[r]);
          acc[r] = fmaf(zv.w, ev.w, acc[r]);
        }
      }
      const float en = enorm[j];
#pragma unroll
      for (int r = 0; r < RPB; ++r) {
        float X = szf[r] + en;
        float Y = 2.0f * acc[r];
        float d = X - Y;
        if (d < bd[r] || (d == bd[r] && j < bi[r])) { bd[r] = d; bi[r] = j; }
      }
    }
#pragma unroll
    for (int r = 0; r < RPB; ++r) { rs[r][tid] = bd[r]; ri[r][tid] = bi[r]; }
    __syncthreads();
    for (int o = 128; o > 0; o >>= 1) {
      if (tid < o) {
#pragma unroll
        for (int r = 0; r < RPB; ++r) {
          float os = rs[r][tid + o]; int oi = ri[r][tid + o];
          if (os < rs[r][tid] || (os == rs[r][tid] && oi < ri[r][tid])) {
            rs[r][tid] = os; ri[r][tid] = oi;
          }
        }
      }
      __syncthreads();
    }
    if (tid < RPB) {
      int wi = base + tid;
      if (wi < cnt) {
        int n = worklist[wi];
        int old = idx_i[n];
        int nw = ri[tid][0];
        if (nw != old) {
          idx_i[n] = nw; idx_f[n] = (float)nw;
          atomicAdd(&counts[old], -1);
          atomicAdd(&counts[nw], 1);
        }
      }
    }
    __syncthreads();
  }
}

// Tiled gather: per block a 32t x 256c tile of one batch.
__launch_bounds__(256, 4)
__global__ void k_gather(const float* __restrict__ z, const float* __restrict__ emb,
                         const int* __restrict__ idxv, float* __restrict__ zq,
                         float* __restrict__ sse) {
  __shared__ int ids[32];
  __shared__ float tile[32 * 260];
  __shared__ float wsum[4];
  const int tid = threadIdx.x;
  const int blk = blockIdx.x;
  const int b = blk >> 6;
  const int t0 = (blk & 63) << 5;
  const int n0 = (b << 11) + t0;
  if (tid < 32) ids[tid] = idxv[n0 + tid];
  __syncthreads();
  const int r = tid & 31;   // t within tile
  const int q = tid >> 5;   // c-quarter 0..7 (32 c each)
  {
    const float4* er = reinterpret_cast<const float4*>(emb) + ((size_t)ids[r] << 6) + (q << 3);
    float4* dst = reinterpret_cast<float4*>(&tile[r * 260 + (q << 5)]);
#pragma unroll
    for (int j = 0; j < 8; ++j) dst[j] = er[j];
  }
  __syncthreads();
  float local = 0.f;
  const size_t base = (((size_t)b << 8) << 11) + t0;  // b*256*2048 + t0
#pragma unroll 8
  for (int it = 0; it < 32; ++it) {
    const int c = (it << 3) + q;
    const float qv = tile[r * 260 + c];
    const size_t g = base + ((size_t)c << 11) + r;
    const float zv = z[g];
    zq[g] = qv;
    const float d = qv - zv;
    local = fmaf(d, d, local);
  }
#pragma unroll
  for (int m = 32; m > 0; m >>= 1) local += __shfl_down(local, m);
  if ((tid & 63) == 0) wsum[tid >> 6] = local;
  __syncthreads();
  if (tid == 0) atomicAdd(sse, wsum[0] + wsum[1] + wsum[2] + wsum[3]);
}

__global__ void k_final(const int* __restrict__ counts, const float* __restrict__ sse,
                        float* __restrict__ out_loss, float* __restrict__ out_perp) {
  __shared__ float red[256];
  int tid = threadIdx.x;
  float s = 0.f;
  for (int j = tid; j < NE_; j += 256) {
    float em = (float)counts[j] * (1.0f / (float)N_);
    s += em * logf(em + 1e-10f);
  }
  red[tid] = s;
  __syncthreads();
  for (int o = 128; o > 0; o >>= 1) {
    if (tid < o) red[tid] += red[tid + o];
    __syncthreads();
  }
  if (tid == 0) {
    out_perp[0] = expf(-red[0]);
    out_loss[0] = (0.25f + 1.0f) * sse[0] / (float)NELEM;
  }
}

extern "C" void kernel_launch(void* const* d_in, const int* in_sizes, int n_in,
                              void* d_out, int out_size, void* d_ws, size_t ws_size,
                              hipStream_t stream) {
  const float* z = (const float*)d_in[0];
  const float* emb = (const float*)d_in[1];
  float* out = (float*)d_out;
  float* zq_out = out;
  float* out_loss = out + NELEM;
  float* out_perp = out + NELEM + 1;
  float* out_idx = out + NELEM + 2;

  int* ws_counts = (int*)d_ws;
  float* ws_enorm = (float*)d_ws + 1024;
  float* ws_sse = (float*)d_ws + 2048;
  int* ws_nflag = (int*)d_ws + 2049;
  int* ws_idx = (int*)d_ws + 4608;
  int* ws_worklist = (int*)d_ws + 70144;
  half8* ws_ebuf = (half8*)((float*)d_ws + 98304);

  hipMemsetAsync(d_ws, 0, 8224, stream);

  k_prep<<<NE_ / 256, 256, 0, stream>>>(emb, ws_ebuf, ws_enorm);
  k_vq<<<N_ / 64, 256, 0, stream>>>(z, ws_ebuf, ws_enorm, ws_idx, out_idx,
                                    ws_counts, ws_nflag, ws_worklist);
  k_repair<<<2048, 256, 0, stream>>>(z, emb, ws_enorm, ws_nflag, ws_worklist,
                                     ws_idx, out_idx, ws_counts);
  k_gather<<<2048, 256, 0, stream>>>(z, emb, ws_idx, zq_out, ws_sse);
  k_final<<<1, 256, 0, stream>>>(ws_counts, ws_sse, out_loss, out_perp);
}

// Round 8
// 479.433 us; speedup vs baseline: 1.8917x; 1.8917x over previous
//
#include <hip/hip_runtime.h>

#define B_ 32
#define C_ 256
#define T_ 2048
#define N_ 65536      // B_*T_
#define NE_ 1024
#define NELEM 16777216  // B_*C_*T_
#define TAU 1.75e-4f    // repair window: np fp32 quantization (~3.2e-5) + f16 GEMM noise, >1.5x margin
#define WLCAP 16384
#define RPB 8           // flagged rows per repair block

typedef _Float16 half8 __attribute__((ext_vector_type(8)));
typedef float f32x16 __attribute__((ext_vector_type(16)));

// d_ws layout (4-byte units):
// [0,1024)        counts (int)
// [1024,2048)     enorm (float, fl32 of fp64-exact ||e||^2)
// [2048]          sse (float)
// [2049]          nflag (int)
// [4608,70144)    idx (int)
// [70144,86528)   worklist (int)
// [98304,229376)  ebuf: e as f16 in MFMA B-fragment order (512 KB)

__global__ void k_prep(const float* __restrict__ emb, half8* __restrict__ ebuf,
                       float* __restrict__ enorm) {
  int code = blockIdx.x * blockDim.x + threadIdx.x;  // 0..1023
  const float4* row = reinterpret_cast<const float4*>(emb + (size_t)code * C_);
  double s = 0.0;
#pragma unroll
  for (int k = 0; k < C_ / 4; ++k) {
    float4 v = row[k];
    s = fma((double)v.x, (double)v.x, s);
    s = fma((double)v.y, (double)v.y, s);
    s = fma((double)v.z, (double)v.z, s);
    s = fma((double)v.w, (double)v.w, s);
  }
  enorm[code] = (float)s;
  const int nt = code >> 5, lcol = code & 31;
#pragma unroll
  for (int s16 = 0; s16 < 16; ++s16) {
#pragma unroll
    for (int h2 = 0; h2 < 2; ++h2) {
      float4 v0 = row[s16 * 4 + h2 * 2];
      float4 v1 = row[s16 * 4 + h2 * 2 + 1];
      half8 hv;
      hv[0] = (_Float16)v0.x; hv[1] = (_Float16)v0.y;
      hv[2] = (_Float16)v0.z; hv[3] = (_Float16)v0.w;
      hv[4] = (_Float16)v1.x; hv[5] = (_Float16)v1.y;
      hv[6] = (_Float16)v1.z; hv[7] = (_Float16)v1.w;
      ebuf[(nt * 16 + s16) * 64 + h2 * 32 + lcol] = hv;
    }
  }
}

// MFMA VQ (hi-only f16): per wave 32 rows x 1024 codes. B double-buffered in
// LDS, shared by the block's 4 waves; reg-staged prefetch 2 tiles ahead.
// Fold/merge semantics identical to the round-6 passing version.
__launch_bounds__(256, 2)
__global__ void k_vq(const float* __restrict__ z, const half8* __restrict__ ebuf,
                     const float* __restrict__ enorm, int* __restrict__ idx_i,
                     float* __restrict__ idx_f, int* __restrict__ counts,
                     int* __restrict__ nflag, int* __restrict__ worklist) {
  __shared__ half8 Bs[2][1024];  // 2 x 16 KB
  const int tid = threadIdx.x;
  const int w = tid >> 6;        // wave 0..3
  const int l = tid & 63;
  const int lcol = l & 31;       // A-row slot / B-col slot
  const int h2 = l >> 5;         // k-group
  const int n0 = blockIdx.x * 128;
  const int b = n0 >> 11;
  const int t = (n0 & (T_ - 1)) + w * 32 + lcol;
  const float* zcol = z + (size_t)b * C_ * T_ + t;

  // A fragments: 32 rows x 256 k, hi f16 only (64 VGPRs)
  half8 Ah[16];
#pragma unroll
  for (int s = 0; s < 16; ++s) {
    half8 hv;
#pragma unroll
    for (int i = 0; i < 8; ++i) {
      float zf = zcol[(size_t)(16 * s + 8 * h2 + i) * T_];
      hv[i] = (_Float16)zf;
    }
    Ah[s] = hv;
  }

  const float4* eb4 = reinterpret_cast<const float4*>(ebuf);
  float4* bs0 = reinterpret_cast<float4*>(&Bs[0][0]);
  float4* bs1 = reinterpret_cast<float4*>(&Bs[1][0]);

  // prologue: stage nt=0 into Bs[0], prefetch nt=1 into regs
  float4 stg[4];
#pragma unroll
  for (int j = 0; j < 4; ++j) stg[j] = eb4[0 * 1024 + j * 256 + tid];
#pragma unroll
  for (int j = 0; j < 4; ++j) bs0[j * 256 + tid] = stg[j];
#pragma unroll
  for (int j = 0; j < 4; ++j) stg[j] = eb4[1 * 1024 + j * 256 + tid];
  __syncthreads();

  f32x16 Z;
#pragma unroll
  for (int r = 0; r < 16; ++r) Z[r] = 0.f;

  float b1s[16], b2s[16]; int b1i[16];
#pragma unroll
  for (int r = 0; r < 16; ++r) { b1s[r] = 3.4e38f; b2s[r] = 3.4e38f; b1i[r] = 0; }

  int cur = 0;
  for (int nt = 0; nt < 32; ++nt) {
    const half8* bp = &Bs[cur][l];
    f32x16 a0 = Z, a1 = Z;  // two independent chains: k 0..127, 128..255
#pragma unroll
    for (int s = 0; s < 8; ++s) {
      a0 = __builtin_amdgcn_mfma_f32_32x32x16_f16(Ah[s], bp[s * 64], a0, 0, 0, 0);
      a1 = __builtin_amdgcn_mfma_f32_32x32x16_f16(Ah[s + 8], bp[(s + 8) * 64], a1, 0, 0, 0);
    }
    const int codeb = (nt << 5) + lcol;
    const float en = enorm[codeb];
#pragma unroll
    for (int r = 0; r < 16; ++r) {
      float sc = fmaf(-2.f, a0[r] + a1[r], en);
      float nb2 = fminf(b2s[r], fmaxf(b1s[r], sc));
      bool lt = sc < b1s[r];
      b2s[r] = nb2;
      b1i[r] = lt ? codeb : b1i[r];
      b1s[r] = fminf(b1s[r], sc);
    }
    __syncthreads();  // all waves done reading Bs[cur]
    if (nt < 31) {
      float4* dst = (cur ? bs0 : bs1);
#pragma unroll
      for (int j = 0; j < 4; ++j) dst[j * 256 + tid] = stg[j];  // write nt+1
      if (nt < 30) {
#pragma unroll
        for (int j = 0; j < 4; ++j)
          stg[j] = eb4[(size_t)(nt + 2) * 1024 + j * 256 + tid];  // prefetch nt+2
      }
      __syncthreads();  // staged writes visible
      cur ^= 1;
    }
  }

  // merge top-2 across the 32 code-lanes (lanes differ in lcol)
#pragma unroll
  for (int m = 1; m < 32; m <<= 1) {
#pragma unroll
    for (int r = 0; r < 16; ++r) {
      float o1 = __shfl_xor(b1s[r], m);
      int oi = __shfl_xor(b1i[r], m);
      float o2 = __shfl_xor(b2s[r], m);
      float hi = fmaxf(b1s[r], o1);
      b2s[r] = fminf(fminf(b2s[r], o2), hi);
      if (o1 < b1s[r] || (o1 == b1s[r] && oi < b1i[r])) { b1s[r] = o1; b1i[r] = oi; }
    }
  }
  if (lcol == 0) {
#pragma unroll
    for (int r = 0; r < 16; ++r) {
      int n = n0 + w * 32 + (r & 3) + ((r >> 2) << 3) + (h2 << 2);
      idx_i[n] = b1i[r];
      idx_f[n] = (float)b1i[r];
      atomicAdd(&counts[b1i[r]], 1);
      if (b2s[r] - b1s[r] < TAU) {
        int p = atomicAdd(nflag, 1);
        if (p < WLCAP) worklist[p] = n;
      }
    }
  }
}

// Re-score flagged rows (batched RPB per block) emulating numpy's fp32 arithmetic.
__global__ void k_repair(const float* __restrict__ z, const float* __restrict__ emb,
                         const float* __restrict__ enorm,
                         const int* __restrict__ nflag, const int* __restrict__ worklist,
                         int* __restrict__ idx_i, float* __restrict__ idx_f,
                         int* __restrict__ counts) {
  __shared__ float4 zs4[RPB][C_ / 4];
  __shared__ double wred[4][RPB];
  __shared__ float szf[RPB];
  __shared__ float rs[RPB][256];
  __shared__ int ri[RPB][256];
  const int tid = threadIdx.x;
  int cnt = nflag[0];
  if (cnt > WLCAP) cnt = WLCAP;
  const int nbatch = (cnt + RPB - 1) / RPB;
  for (int batch = blockIdx.x; batch < nbatch; batch += gridDim.x) {
    const int base = batch * RPB;
    double p[RPB];
#pragma unroll
    for (int r = 0; r < RPB; ++r) {
      int wi = base + r;
      int n = worklist[wi < cnt ? wi : base];
      int b = n >> 11, t = n & (T_ - 1);
      float zv = z[(size_t)b * C_ * T_ + (size_t)tid * T_ + t];
      reinterpret_cast<float*>(&zs4[r][0])[tid] = zv;
      p[r] = (double)zv * (double)zv;
    }
#pragma unroll
    for (int m = 32; m > 0; m >>= 1)
#pragma unroll
      for (int r = 0; r < RPB; ++r) p[r] += __shfl_down(p[r], m);
    if ((tid & 63) == 0)
#pragma unroll
      for (int r = 0; r < RPB; ++r) wred[tid >> 6][r] = p[r];
    __syncthreads();
    if (tid < RPB)
      szf[tid] = (float)(wred[0][tid] + wred[1][tid] + wred[2][tid] + wred[3][tid]);
    __syncthreads();

    float bd[RPB]; int bi[RPB];
#pragma unroll
    for (int r = 0; r < RPB; ++r) { bd[r] = 3.4e38f; bi[r] = 1 << 30; }
#pragma unroll
    for (int rep = 0; rep < 4; ++rep) {
      const int j = rep * 256 + tid;
      const float4* er = reinterpret_cast<const float4*>(emb + (size_t)j * C_);
      float acc[RPB];
#pragma unroll
      for (int r = 0; r < RPB; ++r) acc[r] = 0.f;
#pragma unroll 8
      for (int k4 = 0; k4 < C_ / 4; ++k4) {
        float4 ev = er[k4];
#pragma unroll
        for (int r = 0; r < RPB; ++r) {
          float4 zv = zs4[r][k4];
          acc[r] = fmaf(zv.x, ev.x, acc[r]);
          acc[r] = fmaf(zv.y, ev.y, acc[r]);
          acc[r] = fmaf(zv.z, ev.z, acc[r]);
          acc[r] = fmaf(zv.w, ev.w, acc[r]);
        }
      }
      const float en = enorm[j];
#pragma unroll
      for (int r = 0; r < RPB; ++r) {
        float X = szf[r] + en;
        float Y = 2.0f * acc[r];
        float d = X - Y;
        if (d < bd[r] || (d == bd[r] && j < bi[r])) { bd[r] = d; bi[r] = j; }
      }
    }
#pragma unroll
    for (int r = 0; r < RPB; ++r) { rs[r][tid] = bd[r]; ri[r][tid] = bi[r]; }
    __syncthreads();
    for (int o = 128; o > 0; o >>= 1) {
      if (tid < o) {
#pragma unroll
        for (int r = 0; r < RPB; ++r) {
          float os = rs[r][tid + o]; int oi = ri[r][tid + o];
          if (os < rs[r][tid] || (os == rs[r][tid] && oi < ri[r][tid])) {
            rs[r][tid] = os; ri[r][tid] = oi;
          }
        }
      }
      __syncthreads();
    }
    if (tid < RPB) {
      int wi = base + tid;
      if (wi < cnt) {
        int n = worklist[wi];
        int old = idx_i[n];
        int nw = ri[tid][0];
        if (nw != old) {
          idx_i[n] = nw; idx_f[n] = (float)nw;
          atomicAdd(&counts[old], -1);
          atomicAdd(&counts[nw], 1);
        }
      }
    }
    __syncthreads();
  }
}

// Tiled gather: per block a 32t x 256c tile of one batch.
__launch_bounds__(256, 4)
__global__ void k_gather(const float* __restrict__ z, const float* __restrict__ emb,
                         const int* __restrict__ idxv, float* __restrict__ zq,
                         float* __restrict__ sse) {
  __shared__ int ids[32];
  __shared__ float tile[32 * 260];
  __shared__ float wsum[4];
  const int tid = threadIdx.x;
  const int blk = blockIdx.x;
  const int b = blk >> 6;
  const int t0 = (blk & 63) << 5;
  const int n0 = (b << 11) + t0;
  if (tid < 32) ids[tid] = idxv[n0 + tid];
  __syncthreads();
  const int r = tid & 31;   // t within tile
  const int q = tid >> 5;   // c-quarter 0..7 (32 c each)
  {
    const float4* er = reinterpret_cast<const float4*>(emb) + ((size_t)ids[r] << 6) + (q << 3);
    float4* dst = reinterpret_cast<float4*>(&tile[r * 260 + (q << 5)]);
#pragma unroll
    for (int j = 0; j < 8; ++j) dst[j] = er[j];
  }
  __syncthreads();
  float local = 0.f;
  const size_t base = (((size_t)b << 8) << 11) + t0;  // b*256*2048 + t0
#pragma unroll 8
  for (int it = 0; it < 32; ++it) {
    const int c = (it << 3) + q;
    const float qv = tile[r * 260 + c];
    const size_t g = base + ((size_t)c << 11) + r;
    const float zv = z[g];
    zq[g] = qv;
    const float d = qv - zv;
    local = fmaf(d, d, local);
  }
#pragma unroll
  for (int m = 32; m > 0; m >>= 1) local += __shfl_down(local, m);
  if ((tid & 63) == 0) wsum[tid >> 6] = local;
  __syncthreads();
  if (tid == 0) atomicAdd(sse, wsum[0] + wsum[1] + wsum[2] + wsum[3]);
}

__global__ void k_final(const int* __restrict__ counts, const float* __restrict__ sse,
                        float* __restrict__ out_loss, float* __restrict__ out_perp) {
  __shared__ float red[256];
  int tid = threadIdx.x;
  float s = 0.f;
  for (int j = tid; j < NE_; j += 256) {
    float em = (float)counts[j] * (1.0f / (float)N_);
    s += em * logf(em + 1e-10f);
  }
  red[tid] = s;
  __syncthreads();
  for (int o = 128; o > 0; o >>= 1) {
    if (tid < o) red[tid] += red[tid + o];
    __syncthreads();
  }
  if (tid == 0) {
    out_perp[0] = expf(-red[0]);
    out_loss[0] = (0.25f + 1.0f) * sse[0] / (float)NELEM;
  }
}

extern "C" void kernel_launch(void* const* d_in, const int* in_sizes, int n_in,
                              void* d_out, int out_size, void* d_ws, size_t ws_size,
                              hipStream_t stream) {
  const float* z = (const float*)d_in[0];
  const float* emb = (const float*)d_in[1];
  float* out = (float*)d_out;
  float* zq_out = out;
  float* out_loss = out + NELEM;
  float* out_perp = out + NELEM + 1;
  float* out_idx = out + NELEM + 2;

  int* ws_counts = (int*)d_ws;
  float* ws_enorm = (float*)d_ws + 1024;
  float* ws_sse = (float*)d_ws + 2048;
  int* ws_nflag = (int*)d_ws + 2049;
  int* ws_idx = (int*)d_ws + 4608;
  int* ws_worklist = (int*)d_ws + 70144;
  half8* ws_ebuf = (half8*)((float*)d_ws + 98304);

  hipMemsetAsync(d_ws, 0, 8224, stream);

  k_prep<<<NE_ / 256, 256, 0, stream>>>(emb, ws_ebuf, ws_enorm);
  k_vq<<<N_ / 128, 256, 0, stream>>>(z, ws_ebuf, ws_enorm, ws_idx, out_idx,
                                     ws_counts, ws_nflag, ws_worklist);
  k_repair<<<2048, 256, 0, stream>>>(z, emb, ws_enorm, ws_nflag, ws_worklist,
                                     ws_idx, out_idx, ws_counts);
  k_gather<<<2048, 256, 0, stream>>>(z, emb, ws_idx, zq_out, ws_sse);
  k_final<<<1, 256, 0, stream>>>(ws_counts, ws_sse, out_loss, out_perp);
}

// Round 9
// 443.318 us; speedup vs baseline: 2.0458x; 1.0815x over previous
//
#include <hip/hip_runtime.h>

#define B_ 32
#define C_ 256
#define T_ 2048
#define N_ 65536      // B_*T_
#define NE_ 1024
#define NELEM 16777216  // B_*C_*T_
#define TAU 1.75e-4f    // repair window: np fp32 quantization (~3.2e-5) + f16 GEMM noise, >1.5x margin
#define WLCAP 16384
#define RPB 8           // flagged rows per repair block

typedef _Float16 half8 __attribute__((ext_vector_type(8)));
typedef float f32x16 __attribute__((ext_vector_type(16)));

// d_ws layout (4-byte units):
// [0,1024)        counts (int)
// [1024,2048)     enorm (float, fl32 of fp64-exact ||e||^2)
// [2048]          sse (float)
// [2049]          nflag (int)
// [4608,70144)    idx (int)
// [70144,86528)   worklist (int)
// [98304,229376)  ebuf: e as f16 in MFMA B-fragment order (512 KB)

__global__ void k_prep(const float* __restrict__ emb, half8* __restrict__ ebuf,
                       float* __restrict__ enorm) {
  int code = blockIdx.x * blockDim.x + threadIdx.x;  // 0..1023
  const float4* row = reinterpret_cast<const float4*>(emb + (size_t)code * C_);
  double s = 0.0;
#pragma unroll
  for (int k = 0; k < C_ / 4; ++k) {
    float4 v = row[k];
    s = fma((double)v.x, (double)v.x, s);
    s = fma((double)v.y, (double)v.y, s);
    s = fma((double)v.z, (double)v.z, s);
    s = fma((double)v.w, (double)v.w, s);
  }
  enorm[code] = (float)s;
  const int nt = code >> 5, lcol = code & 31;
#pragma unroll
  for (int s16 = 0; s16 < 16; ++s16) {
#pragma unroll
    for (int h2 = 0; h2 < 2; ++h2) {
      float4 v0 = row[s16 * 4 + h2 * 2];
      float4 v1 = row[s16 * 4 + h2 * 2 + 1];
      half8 hv;
      hv[0] = (_Float16)v0.x; hv[1] = (_Float16)v0.y;
      hv[2] = (_Float16)v0.z; hv[3] = (_Float16)v0.w;
      hv[4] = (_Float16)v1.x; hv[5] = (_Float16)v1.y;
      hv[6] = (_Float16)v1.z; hv[7] = (_Float16)v1.w;
      ebuf[(nt * 16 + s16) * 64 + h2 * 32 + lcol] = hv;
    }
  }
}

// Async-DMA stage of one 16 KB B tile (nt) into LDS; each wave stages its
// quarter via 4x global_load_lds width=16 (LDS dest = wave-uniform base +
// lane*16, linear in lane; global src per-lane). Zero staging VGPRs.
__device__ __forceinline__ void stage_tile(const half8* __restrict__ ebuf,
                                           half8* bsbase, int ntv, int w, int l) {
#pragma unroll
  for (int j = 0; j < 4; ++j) {
    const half8* gp = ebuf + (size_t)ntv * 1024 + (w * 4 + j) * 64 + l;
    half8* lp = bsbase + (w * 4 + j) * 64;
    __builtin_amdgcn_global_load_lds(
        (const __attribute__((address_space(1))) unsigned int*)gp,
        (__attribute__((address_space(3))) unsigned int*)lp, 16, 0, 0);
  }
}

// MFMA VQ (hi-only f16): per wave 32 rows x 1024 codes. B double-buffered in
// LDS via async global_load_lds, shared by the block's 4 waves. Fold/merge
// semantics identical to the round-8 passing version.
__launch_bounds__(256, 2)
__global__ void k_vq(const float* __restrict__ z, const half8* __restrict__ ebuf,
                     const float* __restrict__ enorm, int* __restrict__ idx_i,
                     float* __restrict__ idx_f, int* __restrict__ counts,
                     int* __restrict__ nflag, int* __restrict__ worklist) {
  __shared__ half8 Bs[2][1024];  // 2 x 16 KB
  const int tid = threadIdx.x;
  const int w = tid >> 6;        // wave 0..3
  const int l = tid & 63;
  const int lcol = l & 31;       // A-row slot / B-col slot
  const int h2 = l >> 5;         // k-group
  const int n0 = blockIdx.x * 128;
  const int b = n0 >> 11;
  const int t = (n0 & (T_ - 1)) + w * 32 + lcol;
  const float* zcol = z + (size_t)b * C_ * T_ + t;

  // kick off DMA for nt=0 first; z loads overlap with it
  stage_tile(ebuf, &Bs[0][0], 0, w, l);

  // A fragments: 32 rows x 256 k, hi f16 only (64 VGPRs)
  half8 Ah[16];
#pragma unroll
  for (int s = 0; s < 16; ++s) {
    half8 hv;
#pragma unroll
    for (int i = 0; i < 8; ++i) {
      float zf = zcol[(size_t)(16 * s + 8 * h2 + i) * T_];
      hv[i] = (_Float16)zf;
    }
    Ah[s] = hv;
  }

  f32x16 Z;
#pragma unroll
  for (int r = 0; r < 16; ++r) Z[r] = 0.f;

  float b1s[16], b2s[16]; int b1i[16];
#pragma unroll
  for (int r = 0; r < 16; ++r) { b1s[r] = 3.4e38f; b2s[r] = 3.4e38f; b1i[r] = 0; }

  __syncthreads();  // vmcnt(0): nt=0 DMA (and z loads) complete

  int cur = 0;
  for (int nt = 0; nt < 32; ++nt) {
    if (nt < 31) stage_tile(ebuf, &Bs[cur ^ 1][0], nt + 1, w, l);  // async next tile
    const half8* bp = &Bs[cur][l];
    f32x16 a0 = Z, a1 = Z;  // two independent chains: k 0..127, 128..255
#pragma unroll
    for (int s = 0; s < 8; ++s) {
      a0 = __builtin_amdgcn_mfma_f32_32x32x16_f16(Ah[s], bp[s * 64], a0, 0, 0, 0);
      a1 = __builtin_amdgcn_mfma_f32_32x32x16_f16(Ah[s + 8], bp[(s + 8) * 64], a1, 0, 0, 0);
    }
    const int codeb = (nt << 5) + lcol;
    const float en = enorm[codeb];
#pragma unroll
    for (int r = 0; r < 16; ++r) {
      float sc = fmaf(-2.f, a0[r] + a1[r], en);
      float nb2 = fminf(b2s[r], fmaxf(b1s[r], sc));
      bool lt = sc < b1s[r];
      b2s[r] = nb2;
      b1i[r] = lt ? codeb : b1i[r];
      b1s[r] = fminf(b1s[r], sc);
    }
    __syncthreads();  // drains next-tile DMA (vmcnt 0) + all waves done reading Bs[cur]
    cur ^= 1;
  }

  // merge top-2 across the 32 code-lanes (lanes differ in lcol)
#pragma unroll
  for (int m = 1; m < 32; m <<= 1) {
#pragma unroll
    for (int r = 0; r < 16; ++r) {
      float o1 = __shfl_xor(b1s[r], m);
      int oi = __shfl_xor(b1i[r], m);
      float o2 = __shfl_xor(b2s[r], m);
      float hi = fmaxf(b1s[r], o1);
      b2s[r] = fminf(fminf(b2s[r], o2), hi);
      if (o1 < b1s[r] || (o1 == b1s[r] && oi < b1i[r])) { b1s[r] = o1; b1i[r] = oi; }
    }
  }
  if (lcol == 0) {
#pragma unroll
    for (int r = 0; r < 16; ++r) {
      int n = n0 + w * 32 + (r & 3) + ((r >> 2) << 3) + (h2 << 2);
      idx_i[n] = b1i[r];
      idx_f[n] = (float)b1i[r];
      atomicAdd(&counts[b1i[r]], 1);
      if (b2s[r] - b1s[r] < TAU) {
        int p = atomicAdd(nflag, 1);
        if (p < WLCAP) worklist[p] = n;
      }
    }
  }
}

// Re-score flagged rows (batched RPB per block) emulating numpy's fp32 arithmetic.
__global__ void k_repair(const float* __restrict__ z, const float* __restrict__ emb,
                         const float* __restrict__ enorm,
                         const int* __restrict__ nflag, const int* __restrict__ worklist,
                         int* __restrict__ idx_i, float* __restrict__ idx_f,
                         int* __restrict__ counts) {
  __shared__ float4 zs4[RPB][C_ / 4];
  __shared__ double wred[4][RPB];
  __shared__ float szf[RPB];
  __shared__ float rs[RPB][256];
  __shared__ int ri[RPB][256];
  const int tid = threadIdx.x;
  int cnt = nflag[0];
  if (cnt > WLCAP) cnt = WLCAP;
  const int nbatch = (cnt + RPB - 1) / RPB;
  for (int batch = blockIdx.x; batch < nbatch; batch += gridDim.x) {
    const int base = batch * RPB;
    double p[RPB];
#pragma unroll
    for (int r = 0; r < RPB; ++r) {
      int wi = base + r;
      int n = worklist[wi < cnt ? wi : base];
      int b = n >> 11, t = n & (T_ - 1);
      float zv = z[(size_t)b * C_ * T_ + (size_t)tid * T_ + t];
      reinterpret_cast<float*>(&zs4[r][0])[tid] = zv;
      p[r] = (double)zv * (double)zv;
    }
#pragma unroll
    for (int m = 32; m > 0; m >>= 1)
#pragma unroll
      for (int r = 0; r < RPB; ++r) p[r] += __shfl_down(p[r], m);
    if ((tid & 63) == 0)
#pragma unroll
      for (int r = 0; r < RPB; ++r) wred[tid >> 6][r] = p[r];
    __syncthreads();
    if (tid < RPB)
      szf[tid] = (float)(wred[0][tid] + wred[1][tid] + wred[2][tid] + wred[3][tid]);
    __syncthreads();

    float bd[RPB]; int bi[RPB];
#pragma unroll
    for (int r = 0; r < RPB; ++r) { bd[r] = 3.4e38f; bi[r] = 1 << 30; }
#pragma unroll
    for (int rep = 0; rep < 4; ++rep) {
      const int j = rep * 256 + tid;
      const float4* er = reinterpret_cast<const float4*>(emb + (size_t)j * C_);
      float acc[RPB];
#pragma unroll
      for (int r = 0; r < RPB; ++r) acc[r] = 0.f;
#pragma unroll 8
      for (int k4 = 0; k4 < C_ / 4; ++k4) {
        float4 ev = er[k4];
#pragma unroll
        for (int r = 0; r < RPB; ++r) {
          float4 zv = zs4[r][k4];
          acc[r] = fmaf(zv.x, ev.x, acc[r]);
          acc[r] = fmaf(zv.y, ev.y, acc[r]);
          acc[r] = fmaf(zv.z, ev.z, acc[r]);
          acc[r] = fmaf(zv.w, ev.w, acc[r]);
        }
      }
      const float en = enorm[j];
#pragma unroll
      for (int r = 0; r < RPB; ++r) {
        float X = szf[r] + en;
        float Y = 2.0f * acc[r];
        float d = X - Y;
        if (d < bd[r] || (d == bd[r] && j < bi[r])) { bd[r] = d; bi[r] = j; }
      }
    }
#pragma unroll
    for (int r = 0; r < RPB; ++r) { rs[r][tid] = bd[r]; ri[r][tid] = bi[r]; }
    __syncthreads();
    for (int o = 128; o > 0; o >>= 1) {
      if (tid < o) {
#pragma unroll
        for (int r = 0; r < RPB; ++r) {
          float os = rs[r][tid + o]; int oi = ri[r][tid + o];
          if (os < rs[r][tid] || (os == rs[r][tid] && oi < ri[r][tid])) {
            rs[r][tid] = os; ri[r][tid] = oi;
          }
        }
      }
      __syncthreads();
    }
    if (tid < RPB) {
      int wi = base + tid;
      if (wi < cnt) {
        int n = worklist[wi];
        int old = idx_i[n];
        int nw = ri[tid][0];
        if (nw != old) {
          idx_i[n] = nw; idx_f[n] = (float)nw;
          atomicAdd(&counts[old], -1);
          atomicAdd(&counts[nw], 1);
        }
      }
    }
    __syncthreads();
  }
}

// Tiled gather: per block a 32t x 256c tile of one batch.
__launch_bounds__(256, 4)
__global__ void k_gather(const float* __restrict__ z, const float* __restrict__ emb,
                         const int* __restrict__ idxv, float* __restrict__ zq,
                         float* __restrict__ sse) {
  __shared__ int ids[32];
  __shared__ float tile[32 * 260];
  __shared__ float wsum[4];
  const int tid = threadIdx.x;
  const int blk = blockIdx.x;
  const int b = blk >> 6;
  const int t0 = (blk & 63) << 5;
  const int n0 = (b << 11) + t0;
  if (tid < 32) ids[tid] = idxv[n0 + tid];
  __syncthreads();
  const int r = tid & 31;   // t within tile
  const int q = tid >> 5;   // c-quarter 0..7 (32 c each)
  {
    const float4* er = reinterpret_cast<const float4*>(emb) + ((size_t)ids[r] << 6) + (q << 3);
    float4* dst = reinterpret_cast<float4*>(&tile[r * 260 + (q << 5)]);
#pragma unroll
    for (int j = 0; j < 8; ++j) dst[j] = er[j];
  }
  __syncthreads();
  float local = 0.f;
  const size_t base = (((size_t)b << 8) << 11) + t0;  // b*256*2048 + t0
#pragma unroll 8
  for (int it = 0; it < 32; ++it) {
    const int c = (it << 3) + q;
    const float qv = tile[r * 260 + c];
    const size_t g = base + ((size_t)c << 11) + r;
    const float zv = z[g];
    zq[g] = qv;
    const float d = qv - zv;
    local = fmaf(d, d, local);
  }
#pragma unroll
  for (int m = 32; m > 0; m >>= 1) local += __shfl_down(local, m);
  if ((tid & 63) == 0) wsum[tid >> 6] = local;
  __syncthreads();
  if (tid == 0) atomicAdd(sse, wsum[0] + wsum[1] + wsum[2] + wsum[3]);
}

__global__ void k_final(const int* __restrict__ counts, const float* __restrict__ sse,
                        float* __restrict__ out_loss, float* __restrict__ out_perp) {
  __shared__ float red[256];
  int tid = threadIdx.x;
  float s = 0.f;
  for (int j = tid; j < NE_; j += 256) {
    float em = (float)counts[j] * (1.0f / (float)N_);
    s += em * logf(em + 1e-10f);
  }
  red[tid] = s;
  __syncthreads();
  for (int o = 128; o > 0; o >>= 1) {
    if (tid < o) red[tid] += red[tid + o];
    __syncthreads();
  }
  if (tid == 0) {
    out_perp[0] = expf(-red[0]);
    out_loss[0] = (0.25f + 1.0f) * sse[0] / (float)NELEM;
  }
}

extern "C" void kernel_launch(void* const* d_in, const int* in_sizes, int n_in,
                              void* d_out, int out_size, void* d_ws, size_t ws_size,
                              hipStream_t stream) {
  const float* z = (const float*)d_in[0];
  const float* emb = (const float*)d_in[1];
  float* out = (float*)d_out;
  float* zq_out = out;
  float* out_loss = out + NELEM;
  float* out_perp = out + NELEM + 1;
  float* out_idx = out + NELEM + 2;

  int* ws_counts = (int*)d_ws;
  float* ws_enorm = (float*)d_ws + 1024;
  float* ws_sse = (float*)d_ws + 2048;
  int* ws_nflag = (int*)d_ws + 2049;
  int* ws_idx = (int*)d_ws + 4608;
  int* ws_worklist = (int*)d_ws + 70144;
  half8* ws_ebuf = (half8*)((float*)d_ws + 98304);

  hipMemsetAsync(d_ws, 0, 8224, stream);

  k_prep<<<NE_ / 256, 256, 0, stream>>>(emb, ws_ebuf, ws_enorm);
  k_vq<<<N_ / 128, 256, 0, stream>>>(z, ws_ebuf, ws_enorm, ws_idx, out_idx,
                                     ws_counts, ws_nflag, ws_worklist);
  k_repair<<<2048, 256, 0, stream>>>(z, emb, ws_enorm, ws_nflag, ws_worklist,
                                     ws_idx, out_idx, ws_counts);
  k_gather<<<2048, 256, 0, stream>>>(z, emb, ws_idx, zq_out, ws_sse);
  k_final<<<1, 256, 0, stream>>>(ws_counts, ws_sse, out_loss, out_perp);
}

// Round 10
// 257.421 us; speedup vs baseline: 3.5232x; 1.7222x over previous
//
#include <hip/hip_runtime.h>

#define B_ 32
#define C_ 256
#define T_ 2048
#define N_ 65536      // B_*T_
#define NE_ 1024
#define NELEM 16777216  // B_*C_*T_
#define TAU 1.75e-4f    // repair window: np fp32 quantization (~3.2e-5) + f16 GEMM noise, >1.5x margin
#define WLCAP 16384
#define RPB 8           // flagged rows per repair block

typedef _Float16 half8 __attribute__((ext_vector_type(8)));
typedef float f32x4 __attribute__((ext_vector_type(4)));

// d_ws layout (4-byte units):
// [0,1024)        counts (int)
// [1024,2048)     enorm (float, fl32 of fp64-exact ||e||^2)
// [2048]          sse (float)
// [2049]          nflag (int)
// [4608,70144)    idx (int)
// [70144,86528)   worklist (int)
// [98304,229376)  ebuf: e as f16 in 16x16x32 MFMA B-fragment order (512 KB)

// B-frag map (16x16x32, symmetric with A's map; any consistent k-bijection is
// correct): chunk (ct, s) holds B[k=32s+8g+i][col=ct*16+c] at
// ebuf[(ct*8+s)*64 + g*16 + c][i].
__global__ void k_prep(const float* __restrict__ emb, half8* __restrict__ ebuf,
                       float* __restrict__ enorm) {
  int code = blockIdx.x * blockDim.x + threadIdx.x;  // 0..1023
  const float4* row = reinterpret_cast<const float4*>(emb + (size_t)code * C_);
  double sum = 0.0;
#pragma unroll
  for (int k = 0; k < C_ / 4; ++k) {
    float4 v = row[k];
    sum = fma((double)v.x, (double)v.x, sum);
    sum = fma((double)v.y, (double)v.y, sum);
    sum = fma((double)v.z, (double)v.z, sum);
    sum = fma((double)v.w, (double)v.w, sum);
  }
  enorm[code] = (float)sum;
  const int ct = code >> 4, c = code & 15;
#pragma unroll
  for (int s = 0; s < 8; ++s) {
#pragma unroll
    for (int g = 0; g < 4; ++g) {
      float4 v0 = row[s * 8 + g * 2];
      float4 v1 = row[s * 8 + g * 2 + 1];
      half8 hv;
      hv[0] = (_Float16)v0.x; hv[1] = (_Float16)v0.y;
      hv[2] = (_Float16)v0.z; hv[3] = (_Float16)v0.w;
      hv[4] = (_Float16)v1.x; hv[5] = (_Float16)v1.y;
      hv[6] = (_Float16)v1.z; hv[7] = (_Float16)v1.w;
      ebuf[(ct * 8 + s) * 64 + g * 16 + c] = hv;
    }
  }
}

// MFMA VQ (hi-only f16, 16x16x32): per wave 32 rows x 1024 codes, barrier-free,
// B streamed per-wave from L2. 4 independent MFMA chains (2 row-tiles x 2
// code-tiles) for ILP; grid fixes occupancy at 2 waves/EU so registers are free.
__launch_bounds__(256, 2)
__global__ void k_vq(const float* __restrict__ z, const half8* __restrict__ ebuf,
                     const float* __restrict__ enorm, int* __restrict__ idx_i,
                     float* __restrict__ idx_f, int* __restrict__ counts,
                     int* __restrict__ nflag, int* __restrict__ worklist) {
  const int tid = threadIdx.x;
  const int w = tid >> 6;        // wave 0..3
  const int l = tid & 63;
  const int col = l & 15;        // A-row slot / B-col slot / C-col
  const int g = l >> 4;          // k-group 0..3 (A/B), C row-group
  const int n0 = blockIdx.x * 128;
  const int b = n0 >> 11;
  const int t0 = (n0 & (T_ - 1)) + w * 32;
  const float* zc0 = z + (size_t)b * C_ * T_ + t0 + col;        // row-tile 0
  const float* zc1 = zc0 + 16;                                  // row-tile 1

  // A fragments: rows (l&15) of each 16-row tile, k = 32s + 8g + i. 64 VGPRs.
  half8 A0[8], A1[8];
#pragma unroll
  for (int s = 0; s < 8; ++s) {
    half8 h0, h1;
#pragma unroll
    for (int i = 0; i < 8; ++i) {
      const size_t ko = (size_t)(32 * s + 8 * g + i) * T_;
      h0[i] = (_Float16)zc0[ko];
      h1[i] = (_Float16)zc1[ko];
    }
    A0[s] = h0; A1[s] = h1;
  }

  float b1s[2][4], b2s[2][4]; int b1i[2][4];
#pragma unroll
  for (int rt = 0; rt < 2; ++rt)
#pragma unroll
    for (int q = 0; q < 4; ++q) { b1s[rt][q] = 3.4e38f; b2s[rt][q] = 3.4e38f; b1i[rt][q] = 0; }

  const half8* bp = ebuf + l;
  for (int ctp = 0; ctp < 32; ++ctp) {
    const int ct0 = ctp * 2, ct1 = ct0 + 1;
    f32x4 a00 = {0.f, 0.f, 0.f, 0.f}, a01 = a00, a10 = a00, a11 = a00;
    const half8* p0 = bp + (size_t)(ct0 * 8) * 64;
    const half8* p1 = bp + (size_t)(ct1 * 8) * 64;
#pragma unroll
    for (int s = 0; s < 8; ++s) {
      half8 bf0 = p0[s * 64];
      half8 bf1 = p1[s * 64];
      a00 = __builtin_amdgcn_mfma_f32_16x16x32_f16(A0[s], bf0, a00, 0, 0, 0);
      a10 = __builtin_amdgcn_mfma_f32_16x16x32_f16(A1[s], bf0, a10, 0, 0, 0);
      a01 = __builtin_amdgcn_mfma_f32_16x16x32_f16(A0[s], bf1, a01, 0, 0, 0);
      a11 = __builtin_amdgcn_mfma_f32_16x16x32_f16(A1[s], bf1, a11, 0, 0, 0);
    }
    const float en0 = enorm[ct0 * 16 + col];
    const float en1 = enorm[ct1 * 16 + col];
    const int cb0 = ct0 * 16 + col, cb1 = ct1 * 16 + col;
#pragma unroll
    for (int q = 0; q < 4; ++q) {
      // ct0 first (ascending codes), rt0 and rt1
      {
        float sc = fmaf(-2.f, a00[q], en0);
        float nb2 = fminf(b2s[0][q], fmaxf(b1s[0][q], sc));
        bool lt = sc < b1s[0][q];
        b2s[0][q] = nb2; b1i[0][q] = lt ? cb0 : b1i[0][q]; b1s[0][q] = fminf(b1s[0][q], sc);
      }
      {
        float sc = fmaf(-2.f, a10[q], en0);
        float nb2 = fminf(b2s[1][q], fmaxf(b1s[1][q], sc));
        bool lt = sc < b1s[1][q];
        b2s[1][q] = nb2; b1i[1][q] = lt ? cb0 : b1i[1][q]; b1s[1][q] = fminf(b1s[1][q], sc);
      }
      {
        float sc = fmaf(-2.f, a01[q], en1);
        float nb2 = fminf(b2s[0][q], fmaxf(b1s[0][q], sc));
        bool lt = sc < b1s[0][q];
        b2s[0][q] = nb2; b1i[0][q] = lt ? cb1 : b1i[0][q]; b1s[0][q] = fminf(b1s[0][q], sc);
      }
      {
        float sc = fmaf(-2.f, a11[q], en1);
        float nb2 = fminf(b2s[1][q], fmaxf(b1s[1][q], sc));
        bool lt = sc < b1s[1][q];
        b2s[1][q] = nb2; b1i[1][q] = lt ? cb1 : b1i[1][q]; b1s[1][q] = fminf(b1s[1][q], sc);
      }
    }
  }

  // merge top-2 across the 16 col-lanes of each k-group (masks 1..8 stay in-group)
#pragma unroll
  for (int m = 1; m < 16; m <<= 1) {
#pragma unroll
    for (int rt = 0; rt < 2; ++rt)
#pragma unroll
      for (int q = 0; q < 4; ++q) {
        float o1 = __shfl_xor(b1s[rt][q], m);
        int oi = __shfl_xor(b1i[rt][q], m);
        float o2 = __shfl_xor(b2s[rt][q], m);
        float hi = fmaxf(b1s[rt][q], o1);
        b2s[rt][q] = fminf(fminf(b2s[rt][q], o2), hi);
        if (o1 < b1s[rt][q] || (o1 == b1s[rt][q] && oi < b1i[rt][q])) {
          b1s[rt][q] = o1; b1i[rt][q] = oi;
        }
      }
  }
  if (col == 0) {
#pragma unroll
    for (int rt = 0; rt < 2; ++rt)
#pragma unroll
      for (int q = 0; q < 4; ++q) {
        // C/D map (m89): row = g*4 + q, col folded above
        int n = n0 + w * 32 + rt * 16 + g * 4 + q;
        idx_i[n] = b1i[rt][q];
        idx_f[n] = (float)b1i[rt][q];
        atomicAdd(&counts[b1i[rt][q]], 1);
        if (b2s[rt][q] - b1s[rt][q] < TAU) {
          int p = atomicAdd(nflag, 1);
          if (p < WLCAP) worklist[p] = n;
        }
      }
  }
}

// Re-score flagged rows (batched RPB per block) emulating numpy's fp32 arithmetic.
__global__ void k_repair(const float* __restrict__ z, const float* __restrict__ emb,
                         const float* __restrict__ enorm,
                         const int* __restrict__ nflag, const int* __restrict__ worklist,
                         int* __restrict__ idx_i, float* __restrict__ idx_f,
                         int* __restrict__ counts) {
  __shared__ float4 zs4[RPB][C_ / 4];
  __shared__ double wred[4][RPB];
  __shared__ float szf[RPB];
  __shared__ float rs[RPB][256];
  __shared__ int ri[RPB][256];
  const int tid = threadIdx.x;
  int cnt = nflag[0];
  if (cnt > WLCAP) cnt = WLCAP;
  const int nbatch = (cnt + RPB - 1) / RPB;
  for (int batch = blockIdx.x; batch < nbatch; batch += gridDim.x) {
    const int base = batch * RPB;
    double p[RPB];
#pragma unroll
    for (int r = 0; r < RPB; ++r) {
      int wi = base + r;
      int n = worklist[wi < cnt ? wi : base];
      int b = n >> 11, t = n & (T_ - 1);
      float zv = z[(size_t)b * C_ * T_ + (size_t)tid * T_ + t];
      reinterpret_cast<float*>(&zs4[r][0])[tid] = zv;
      p[r] = (double)zv * (double)zv;
    }
#pragma unroll
    for (int m = 32; m > 0; m >>= 1)
#pragma unroll
      for (int r = 0; r < RPB; ++r) p[r] += __shfl_down(p[r], m);
    if ((tid & 63) == 0)
#pragma unroll
      for (int r = 0; r < RPB; ++r) wred[tid >> 6][r] = p[r];
    __syncthreads();
    if (tid < RPB)
      szf[tid] = (float)(wred[0][tid] + wred[1][tid] + wred[2][tid] + wred[3][tid]);
    __syncthreads();

    float bd[RPB]; int bi[RPB];
#pragma unroll
    for (int r = 0; r < RPB; ++r) { bd[r] = 3.4e38f; bi[r] = 1 << 30; }
#pragma unroll
    for (int rep = 0; rep < 4; ++rep) {
      const int j = rep * 256 + tid;
      const float4* er = reinterpret_cast<const float4*>(emb + (size_t)j * C_);
      float acc[RPB];
#pragma unroll
      for (int r = 0; r < RPB; ++r) acc[r] = 0.f;
#pragma unroll 8
      for (int k4 = 0; k4 < C_ / 4; ++k4) {
        float4 ev = er[k4];
#pragma unroll
        for (int r = 0; r < RPB; ++r) {
          float4 zv = zs4[r][k4];
          acc[r] = fmaf(zv.x, ev.x, acc[r]);
          acc[r] = fmaf(zv.y, ev.y, acc[r]);
          acc[r] = fmaf(zv.z, ev.z, acc[r]);
          acc[r] = fmaf(zv.w, ev.w, acc[r]);
        }
      }
      const float en = enorm[j];
#pragma unroll
      for (int r = 0; r < RPB; ++r) {
        float X = szf[r] + en;
        float Y = 2.0f * acc[r];
        float d = X - Y;
        if (d < bd[r] || (d == bd[r] && j < bi[r])) { bd[r] = d; bi[r] = j; }
      }
    }
#pragma unroll
    for (int r = 0; r < RPB; ++r) { rs[r][tid] = bd[r]; ri[r][tid] = bi[r]; }
    __syncthreads();
    for (int o = 128; o > 0; o >>= 1) {
      if (tid < o) {
#pragma unroll
        for (int r = 0; r < RPB; ++r) {
          float os = rs[r][tid + o]; int oi = ri[r][tid + o];
          if (os < rs[r][tid] || (os == rs[r][tid] && oi < ri[r][tid])) {
            rs[r][tid] = os; ri[r][tid] = oi;
          }
        }
      }
      __syncthreads();
    }
    if (tid < RPB) {
      int wi = base + tid;
      if (wi < cnt) {
        int n = worklist[wi];
        int old = idx_i[n];
        int nw = ri[tid][0];
        if (nw != old) {
          idx_i[n] = nw; idx_f[n] = (float)nw;
          atomicAdd(&counts[old], -1);
          atomicAdd(&counts[nw], 1);
        }
      }
    }
    __syncthreads();
  }
}

// Tiled gather: per block a 32t x 256c tile of one batch.
__launch_bounds__(256, 4)
__global__ void k_gather(const float* __restrict__ z, const float* __restrict__ emb,
                         const int* __restrict__ idxv, float* __restrict__ zq,
                         float* __restrict__ sse) {
  __shared__ int ids[32];
  __shared__ float tile[32 * 260];
  __shared__ float wsum[4];
  const int tid = threadIdx.x;
  const int blk = blockIdx.x;
  const int b = blk >> 6;
  const int t0 = (blk & 63) << 5;
  const int n0 = (b << 11) + t0;
  if (tid < 32) ids[tid] = idxv[n0 + tid];
  __syncthreads();
  const int r = tid & 31;   // t within tile
  const int q = tid >> 5;   // c-quarter 0..7 (32 c each)
  {
    const float4* er = reinterpret_cast<const float4*>(emb) + ((size_t)ids[r] << 6) + (q << 3);
    float4* dst = reinterpret_cast<float4*>(&tile[r * 260 + (q << 5)]);
#pragma unroll
    for (int j = 0; j < 8; ++j) dst[j] = er[j];
  }
  __syncthreads();
  float local = 0.f;
  const size_t base = (((size_t)b << 8) << 11) + t0;  // b*256*2048 + t0
#pragma unroll 8
  for (int it = 0; it < 32; ++it) {
    const int c = (it << 3) + q;
    const float qv = tile[r * 260 + c];
    const size_t gofs = base + ((size_t)c << 11) + r;
    const float zv = z[gofs];
    zq[gofs] = qv;
    const float d = qv - zv;
    local = fmaf(d, d, local);
  }
#pragma unroll
  for (int m = 32; m > 0; m >>= 1) local += __shfl_down(local, m);
  if ((tid & 63) == 0) wsum[tid >> 6] = local;
  __syncthreads();
  if (tid == 0) atomicAdd(sse, wsum[0] + wsum[1] + wsum[2] + wsum[3]);
}

__global__ void k_final(const int* __restrict__ counts, const float* __restrict__ sse,
                        float* __restrict__ out_loss, float* __restrict__ out_perp) {
  __shared__ float red[256];
  int tid = threadIdx.x;
  float s = 0.f;
  for (int j = tid; j < NE_; j += 256) {
    float em = (float)counts[j] * (1.0f / (float)N_);
    s += em * logf(em + 1e-10f);
  }
  red[tid] = s;
  __syncthreads();
  for (int o = 128; o > 0; o >>= 1) {
    if (tid < o) red[tid] += red[tid + o];
    __syncthreads();
  }
  if (tid == 0) {
    out_perp[0] = expf(-red[0]);
    out_loss[0] = (0.25f + 1.0f) * sse[0] / (float)NELEM;
  }
}

extern "C" void kernel_launch(void* const* d_in, const int* in_sizes, int n_in,
                              void* d_out, int out_size, void* d_ws, size_t ws_size,
                              hipStream_t stream) {
  const float* z = (const float*)d_in[0];
  const float* emb = (const float*)d_in[1];
  float* out = (float*)d_out;
  float* zq_out = out;
  float* out_loss = out + NELEM;
  float* out_perp = out + NELEM + 1;
  float* out_idx = out + NELEM + 2;

  int* ws_counts = (int*)d_ws;
  float* ws_enorm = (float*)d_ws + 1024;
  float* ws_sse = (float*)d_ws + 2048;
  int* ws_nflag = (int*)d_ws + 2049;
  int* ws_idx = (int*)d_ws + 4608;
  int* ws_worklist = (int*)d_ws + 70144;
  half8* ws_ebuf = (half8*)((float*)d_ws + 98304);

  hipMemsetAsync(d_ws, 0, 8224, stream);

  k_prep<<<NE_ / 256, 256, 0, stream>>>(emb, ws_ebuf, ws_enorm);
  k_vq<<<N_ / 128, 256, 0, stream>>>(z, ws_ebuf, ws_enorm, ws_idx, out_idx,
                                     ws_counts, ws_nflag, ws_worklist);
  k_repair<<<2048, 256, 0, stream>>>(z, emb, ws_enorm, ws_nflag, ws_worklist,
                                     ws_idx, out_idx, ws_counts);
  k_gather<<<2048, 256, 0, stream>>>(z, emb, ws_idx, zq_out, ws_sse);
  k_final<<<1, 256, 0, stream>>>(ws_counts, ws_sse, out_loss, out_perp);
}

// Round 11
// 237.803 us; speedup vs baseline: 3.8139x; 1.0825x over previous
//
#include <hip/hip_runtime.h>

#define B_ 32
#define C_ 256
#define T_ 2048
#define N_ 65536      // B_*T_
#define NE_ 1024
#define NELEM 16777216  // B_*C_*T_
#define TAU 1.75e-4f    // repair window: np fp32 quantization (~3.2e-5) + f16 GEMM noise, >1.5x margin
#define WLCAP 16384
#define RPB 8           // flagged rows per repair block

typedef _Float16 half8 __attribute__((ext_vector_type(8)));
typedef float f32x4 __attribute__((ext_vector_type(4)));

// d_ws layout (4-byte units):
// [0,1024)        counts (int)
// [1024,2048)     enorm (float, fl32 of fp64-exact ||e||^2)
// [2048]          sse (float)
// [2049]          nflag (int)
// [4608,70144)    idx (int)
// [70144,86528)   worklist (int)
// [98304,229376)  ebuf: e as f16 in 16x16x32 MFMA B-fragment order (512 KB)

// B-frag map (16x16x32, symmetric with A's map; any consistent k-bijection is
// correct): chunk (ct, s) holds B[k=32s+8g+i][col=ct*16+c] at
// ebuf[(ct*8+s)*64 + g*16 + c][i].
__global__ void k_prep(const float* __restrict__ emb, half8* __restrict__ ebuf,
                       float* __restrict__ enorm) {
  int code = blockIdx.x * blockDim.x + threadIdx.x;  // 0..1023
  const float4* row = reinterpret_cast<const float4*>(emb + (size_t)code * C_);
  double sum = 0.0;
#pragma unroll
  for (int k = 0; k < C_ / 4; ++k) {
    float4 v = row[k];
    sum = fma((double)v.x, (double)v.x, sum);
    sum = fma((double)v.y, (double)v.y, sum);
    sum = fma((double)v.z, (double)v.z, sum);
    sum = fma((double)v.w, (double)v.w, sum);
  }
  enorm[code] = (float)sum;
  const int ct = code >> 4, c = code & 15;
#pragma unroll
  for (int s = 0; s < 8; ++s) {
#pragma unroll
    for (int g = 0; g < 4; ++g) {
      float4 v0 = row[s * 8 + g * 2];
      float4 v1 = row[s * 8 + g * 2 + 1];
      half8 hv;
      hv[0] = (_Float16)v0.x; hv[1] = (_Float16)v0.y;
      hv[2] = (_Float16)v0.z; hv[3] = (_Float16)v0.w;
      hv[4] = (_Float16)v1.x; hv[5] = (_Float16)v1.y;
      hv[6] = (_Float16)v1.z; hv[7] = (_Float16)v1.w;
      ebuf[(ct * 8 + s) * 64 + g * 16 + c] = hv;
    }
  }
}

// MFMA VQ (hi-only f16, 16x16x32): per wave 32 rows x 1024 codes, barrier-free.
// Per iteration: batch-issue 16 B loads -> fold previous tile-pair (VALU covers
// load latency) -> 32 MFMAs. Scores/tie-breaks bit-identical to round 10.
__launch_bounds__(256, 2)
__global__ void k_vq(const float* __restrict__ z, const half8* __restrict__ ebuf,
                     const float* __restrict__ enorm, int* __restrict__ idx_i,
                     float* __restrict__ idx_f, int* __restrict__ counts,
                     int* __restrict__ nflag, int* __restrict__ worklist) {
  const int tid = threadIdx.x;
  const int w = tid >> 6;        // wave 0..3
  const int l = tid & 63;
  const int col = l & 15;        // A-row slot / B-col slot / C-col
  const int g = l >> 4;          // k-group 0..3 (A/B), C row-group
  const int n0 = blockIdx.x * 128;
  const int b = n0 >> 11;
  const int t0 = (n0 & (T_ - 1)) + w * 32;
  const float* zc0 = z + (size_t)b * C_ * T_ + t0 + col;        // row-tile 0
  const float* zc1 = zc0 + 16;                                  // row-tile 1

  // A fragments: rows (l&15) of each 16-row tile, k = 32s + 8g + i. 64 VGPRs.
  half8 A0[8], A1[8];
#pragma unroll
  for (int s = 0; s < 8; ++s) {
    half8 h0, h1;
#pragma unroll
    for (int i = 0; i < 8; ++i) {
      const size_t ko = (size_t)(32 * s + 8 * g + i) * T_;
      h0[i] = (_Float16)zc0[ko];
      h1[i] = (_Float16)zc1[ko];
    }
    A0[s] = h0; A1[s] = h1;
  }

  float b1s[2][4], b2s[2][4]; int b1i[2][4];
#pragma unroll
  for (int rt = 0; rt < 2; ++rt)
#pragma unroll
    for (int q = 0; q < 4; ++q) { b1s[rt][q] = 3.4e38f; b2s[rt][q] = 3.4e38f; b1i[rt][q] = 0; }

  // top-2 fold of one code-tile pair (ascending: cb0 before cb1, strict <)
  auto fold = [&](const f32x4& c00, const f32x4& c10, const f32x4& c01, const f32x4& c11,
                  float en0, float en1, int cb0, int cb1) {
#pragma unroll
    for (int q = 0; q < 4; ++q) {
      {
        float sc = fmaf(-2.f, c00[q], en0);
        float nb2 = fminf(b2s[0][q], fmaxf(b1s[0][q], sc));
        bool lt = sc < b1s[0][q];
        b2s[0][q] = nb2; b1i[0][q] = lt ? cb0 : b1i[0][q]; b1s[0][q] = fminf(b1s[0][q], sc);
      }
      {
        float sc = fmaf(-2.f, c10[q], en0);
        float nb2 = fminf(b2s[1][q], fmaxf(b1s[1][q], sc));
        bool lt = sc < b1s[1][q];
        b2s[1][q] = nb2; b1i[1][q] = lt ? cb0 : b1i[1][q]; b1s[1][q] = fminf(b1s[1][q], sc);
      }
      {
        float sc = fmaf(-2.f, c01[q], en1);
        float nb2 = fminf(b2s[0][q], fmaxf(b1s[0][q], sc));
        bool lt = sc < b1s[0][q];
        b2s[0][q] = nb2; b1i[0][q] = lt ? cb1 : b1i[0][q]; b1s[0][q] = fminf(b1s[0][q], sc);
      }
      {
        float sc = fmaf(-2.f, c11[q], en1);
        float nb2 = fminf(b2s[1][q], fmaxf(b1s[1][q], sc));
        bool lt = sc < b1s[1][q];
        b2s[1][q] = nb2; b1i[1][q] = lt ? cb1 : b1i[1][q]; b1s[1][q] = fminf(b1s[1][q], sc);
      }
    }
  };

  const half8* bp = ebuf + l;
  half8 Bf0[8], Bf1[8];
  // prologue: load ctp=0, compute its accumulators
#pragma unroll
  for (int s = 0; s < 8; ++s) { Bf0[s] = bp[s * 64]; Bf1[s] = bp[(8 + s) * 64]; }
  const f32x4 zero4 = {0.f, 0.f, 0.f, 0.f};
  f32x4 a00 = zero4, a01 = zero4, a10 = zero4, a11 = zero4;
#pragma unroll
  for (int s = 0; s < 8; ++s) {
    a00 = __builtin_amdgcn_mfma_f32_16x16x32_f16(A0[s], Bf0[s], a00, 0, 0, 0);
    a10 = __builtin_amdgcn_mfma_f32_16x16x32_f16(A1[s], Bf0[s], a10, 0, 0, 0);
    a01 = __builtin_amdgcn_mfma_f32_16x16x32_f16(A0[s], Bf1[s], a01, 0, 0, 0);
    a11 = __builtin_amdgcn_mfma_f32_16x16x32_f16(A1[s], Bf1[s], a11, 0, 0, 0);
  }
  float pen0 = enorm[col], pen1 = enorm[16 + col];
  int pcb0 = col, pcb1 = 16 + col;

  for (int ctp = 1; ctp < 32; ++ctp) {
    // issue this iteration's 16 loads (batched; one waitcnt before MFMA use)
#pragma unroll
    for (int s = 0; s < 8; ++s) {
      Bf0[s] = bp[(ctp * 16 + s) * 64];
      Bf1[s] = bp[(ctp * 16 + 8 + s) * 64];
    }
    // fold previous pair (VALU only -> covers load latency)
    fold(a00, a10, a01, a11, pen0, pen1, pcb0, pcb1);
    // MFMA current pair
    a00 = zero4; a01 = zero4; a10 = zero4; a11 = zero4;
#pragma unroll
    for (int s = 0; s < 8; ++s) {
      a00 = __builtin_amdgcn_mfma_f32_16x16x32_f16(A0[s], Bf0[s], a00, 0, 0, 0);
      a10 = __builtin_amdgcn_mfma_f32_16x16x32_f16(A1[s], Bf0[s], a10, 0, 0, 0);
      a01 = __builtin_amdgcn_mfma_f32_16x16x32_f16(A0[s], Bf1[s], a01, 0, 0, 0);
      a11 = __builtin_amdgcn_mfma_f32_16x16x32_f16(A1[s], Bf1[s], a11, 0, 0, 0);
    }
    pen0 = enorm[ctp * 32 + col]; pen1 = enorm[ctp * 32 + 16 + col];
    pcb0 = ctp * 32 + col;        pcb1 = ctp * 32 + 16 + col;
  }
  fold(a00, a10, a01, a11, pen0, pen1, pcb0, pcb1);

  // merge top-2 across the 16 col-lanes of each k-group (masks 1..8 stay in-group)
#pragma unroll
  for (int m = 1; m < 16; m <<= 1) {
#pragma unroll
    for (int rt = 0; rt < 2; ++rt)
#pragma unroll
      for (int q = 0; q < 4; ++q) {
        float o1 = __shfl_xor(b1s[rt][q], m);
        int oi = __shfl_xor(b1i[rt][q], m);
        float o2 = __shfl_xor(b2s[rt][q], m);
        float hi = fmaxf(b1s[rt][q], o1);
        b2s[rt][q] = fminf(fminf(b2s[rt][q], o2), hi);
        if (o1 < b1s[rt][q] || (o1 == b1s[rt][q] && oi < b1i[rt][q])) {
          b1s[rt][q] = o1; b1i[rt][q] = oi;
        }
      }
  }
  if (col == 0) {
#pragma unroll
    for (int rt = 0; rt < 2; ++rt)
#pragma unroll
      for (int q = 0; q < 4; ++q) {
        // C/D map (m89): row = g*4 + q
        int n = n0 + w * 32 + rt * 16 + g * 4 + q;
        idx_i[n] = b1i[rt][q];
        idx_f[n] = (float)b1i[rt][q];
        atomicAdd(&counts[b1i[rt][q]], 1);
        if (b2s[rt][q] - b1s[rt][q] < TAU) {
          int p = atomicAdd(nflag, 1);
          if (p < WLCAP) worklist[p] = n;
        }
      }
  }
}

// Re-score flagged rows (batched RPB per block) emulating numpy's fp32 arithmetic.
__global__ void k_repair(const float* __restrict__ z, const float* __restrict__ emb,
                         const float* __restrict__ enorm,
                         const int* __restrict__ nflag, const int* __restrict__ worklist,
                         int* __restrict__ idx_i, float* __restrict__ idx_f,
                         int* __restrict__ counts) {
  __shared__ float4 zs4[RPB][C_ / 4];
  __shared__ double wred[4][RPB];
  __shared__ float szf[RPB];
  __shared__ float rs[RPB][256];
  __shared__ int ri[RPB][256];
  const int tid = threadIdx.x;
  int cnt = nflag[0];
  if (cnt > WLCAP) cnt = WLCAP;
  const int nbatch = (cnt + RPB - 1) / RPB;
  for (int batch = blockIdx.x; batch < nbatch; batch += gridDim.x) {
    const int base = batch * RPB;
    double p[RPB];
#pragma unroll
    for (int r = 0; r < RPB; ++r) {
      int wi = base + r;
      int n = worklist[wi < cnt ? wi : base];
      int b = n >> 11, t = n & (T_ - 1);
      float zv = z[(size_t)b * C_ * T_ + (size_t)tid * T_ + t];
      reinterpret_cast<float*>(&zs4[r][0])[tid] = zv;
      p[r] = (double)zv * (double)zv;
    }
#pragma unroll
    for (int m = 32; m > 0; m >>= 1)
#pragma unroll
      for (int r = 0; r < RPB; ++r) p[r] += __shfl_down(p[r], m);
    if ((tid & 63) == 0)
#pragma unroll
      for (int r = 0; r < RPB; ++r) wred[tid >> 6][r] = p[r];
    __syncthreads();
    if (tid < RPB)
      szf[tid] = (float)(wred[0][tid] + wred[1][tid] + wred[2][tid] + wred[3][tid]);
    __syncthreads();

    float bd[RPB]; int bi[RPB];
#pragma unroll
    for (int r = 0; r < RPB; ++r) { bd[r] = 3.4e38f; bi[r] = 1 << 30; }
#pragma unroll
    for (int rep = 0; rep < 4; ++rep) {
      const int j = rep * 256 + tid;
      const float4* er = reinterpret_cast<const float4*>(emb + (size_t)j * C_);
      float acc[RPB];
#pragma unroll
      for (int r = 0; r < RPB; ++r) acc[r] = 0.f;
#pragma unroll 8
      for (int k4 = 0; k4 < C_ / 4; ++k4) {
        float4 ev = er[k4];
#pragma unroll
        for (int r = 0; r < RPB; ++r) {
          float4 zv = zs4[r][k4];
          acc[r] = fmaf(zv.x, ev.x, acc[r]);
          acc[r] = fmaf(zv.y, ev.y, acc[r]);
          acc[r] = fmaf(zv.z, ev.z, acc[r]);
          acc[r] = fmaf(zv.w, ev.w, acc[r]);
        }
      }
      const float en = enorm[j];
#pragma unroll
      for (int r = 0; r < RPB; ++r) {
        float X = szf[r] + en;
        float Y = 2.0f * acc[r];
        float d = X - Y;
        if (d < bd[r] || (d == bd[r] && j < bi[r])) { bd[r] = d; bi[r] = j; }
      }
    }
#pragma unroll
    for (int r = 0; r < RPB; ++r) { rs[r][tid] = bd[r]; ri[r][tid] = bi[r]; }
    __syncthreads();
    for (int o = 128; o > 0; o >>= 1) {
      if (tid < o) {
#pragma unroll
        for (int r = 0; r < RPB; ++r) {
          float os = rs[r][tid + o]; int oi = ri[r][tid + o];
          if (os < rs[r][tid] || (os == rs[r][tid] && oi < ri[r][tid])) {
            rs[r][tid] = os; ri[r][tid] = oi;
          }
        }
      }
      __syncthreads();
    }
    if (tid < RPB) {
      int wi = base + tid;
      if (wi < cnt) {
        int n = worklist[wi];
        int old = idx_i[n];
        int nw = ri[tid][0];
        if (nw != old) {
          idx_i[n] = nw; idx_f[n] = (float)nw;
          atomicAdd(&counts[old], -1);
          atomicAdd(&counts[nw], 1);
        }
      }
    }
    __syncthreads();
  }
}

// Tiled gather: per block a 32t x 256c tile of one batch.
__launch_bounds__(256, 4)
__global__ void k_gather(const float* __restrict__ z, const float* __restrict__ emb,
                         const int* __restrict__ idxv, float* __restrict__ zq,
                         float* __restrict__ sse) {
  __shared__ int ids[32];
  __shared__ float tile[32 * 260];
  __shared__ float wsum[4];
  const int tid = threadIdx.x;
  const int blk = blockIdx.x;
  const int b = blk >> 6;
  const int t0 = (blk & 63) << 5;
  const int n0 = (b << 11) + t0;
  if (tid < 32) ids[tid] = idxv[n0 + tid];
  __syncthreads();
  const int r = tid & 31;   // t within tile
  const int q = tid >> 5;   // c-quarter 0..7 (32 c each)
  {
    const float4* er = reinterpret_cast<const float4*>(emb) + ((size_t)ids[r] << 6) + (q << 3);
    float4* dst = reinterpret_cast<float4*>(&tile[r * 260 + (q << 5)]);
#pragma unroll
    for (int j = 0; j < 8; ++j) dst[j] = er[j];
  }
  __syncthreads();
  float local = 0.f;
  const size_t base = (((size_t)b << 8) << 11) + t0;  // b*256*2048 + t0
#pragma unroll 8
  for (int it = 0; it < 32; ++it) {
    const int c = (it << 3) + q;
    const float qv = tile[r * 260 + c];
    const size_t gofs = base + ((size_t)c << 11) + r;
    const float zv = z[gofs];
    zq[gofs] = qv;
    const float d = qv - zv;
    local = fmaf(d, d, local);
  }
#pragma unroll
  for (int m = 32; m > 0; m >>= 1) local += __shfl_down(local, m);
  if ((tid & 63) == 0) wsum[tid >> 6] = local;
  __syncthreads();
  if (tid == 0) atomicAdd(sse, wsum[0] + wsum[1] + wsum[2] + wsum[3]);
}

__global__ void k_final(const int* __restrict__ counts, const float* __restrict__ sse,
                        float* __restrict__ out_loss, float* __restrict__ out_perp) {
  __shared__ float red[256];
  int tid = threadIdx.x;
  float s = 0.f;
  for (int j = tid; j < NE_; j += 256) {
    float em = (float)counts[j] * (1.0f / (float)N_);
    s += em * logf(em + 1e-10f);
  }
  red[tid] = s;
  __syncthreads();
  for (int o = 128; o > 0; o >>= 1) {
    if (tid < o) red[tid] += red[tid + o];
    __syncthreads();
  }
  if (tid == 0) {
    out_perp[0] = expf(-red[0]);
    out_loss[0] = (0.25f + 1.0f) * sse[0] / (float)NELEM;
  }
}

extern "C" void kernel_launch(void* const* d_in, const int* in_sizes, int n_in,
                              void* d_out, int out_size, void* d_ws, size_t ws_size,
                              hipStream_t stream) {
  const float* z = (const float*)d_in[0];
  const float* emb = (const float*)d_in[1];
  float* out = (float*)d_out;
  float* zq_out = out;
  float* out_loss = out + NELEM;
  float* out_perp = out + NELEM + 1;
  float* out_idx = out + NELEM + 2;

  int* ws_counts = (int*)d_ws;
  float* ws_enorm = (float*)d_ws + 1024;
  float* ws_sse = (float*)d_ws + 2048;
  int* ws_nflag = (int*)d_ws + 2049;
  int* ws_idx = (int*)d_ws + 4608;
  int* ws_worklist = (int*)d_ws + 70144;
  half8* ws_ebuf = (half8*)((float*)d_ws + 98304);

  hipMemsetAsync(d_ws, 0, 8224, stream);

  k_prep<<<NE_ / 256, 256, 0, stream>>>(emb, ws_ebuf, ws_enorm);
  k_vq<<<N_ / 128, 256, 0, stream>>>(z, ws_ebuf, ws_enorm, ws_idx, out_idx,
                                     ws_counts, ws_nflag, ws_worklist);
  k_repair<<<2048, 256, 0, stream>>>(z, emb, ws_enorm, ws_nflag, ws_worklist,
                                     ws_idx, out_idx, ws_counts);
  k_gather<<<2048, 256, 0, stream>>>(z, emb, ws_idx, zq_out, ws_sse);
  k_final<<<1, 256, 0, stream>>>(ws_counts, ws_sse, out_loss, out_perp);
}